// Round 9
// baseline (168.167 us; speedup 1.0000x reference)
//
#include <hip/hip_runtime.h>

typedef short bf16x8_t __attribute__((ext_vector_type(8)));
typedef float f32x4_t  __attribute__((ext_vector_type(4)));

#define MFMA16(a,b,c) __builtin_amdgcn_mfma_f32_16x16x32_bf16(a,b,c,0,0,0)
#define CVTPK(lo, hi, dst) asm("v_cvt_pk_bf16_f32 %0, %1, %2" : "=v"(dst) : "v"(lo), "v"(hi))

__device__ __forceinline__ unsigned short f2b(float x){
  unsigned u = __float_as_uint(x);
  u += 0x7fffu + ((u >> 16) & 1u);
  return (unsigned short)(u >> 16);
}

__device__ __forceinline__ void bar_lgkm(){
  asm volatile("s_waitcnt lgkmcnt(0)" ::: "memory");
  __builtin_amdgcn_s_barrier();
  __builtin_amdgcn_sched_barrier(0);
}

// ---------------- setup: weights -> bf16 (blocks 0..255) + n_real (blocks 256..383) ----------------
__global__ void setup_k(const float* __restrict__ kw, const float* __restrict__ vw,
                        const int* __restrict__ mask,
                        unsigned short* __restrict__ wktb, unsigned short* __restrict__ wvb,
                        int* __restrict__ nreal){
  int bid = blockIdx.x, tid = threadIdx.x;
  if (bid < 256){
    int i = bid * 256 + tid;                       // 0..65535
    int d = i >> 8, e = i & 255;
    wktb[i] = f2b(kw[e * 256 + d]);                // WkT[d][e] (transposed, for calc_qkp)
    wvb[i]  = f2b(vw[i]);                          // value_w as-is (for vproj_norm)
  } else {
    int b = (bid - 256) * 4 + (tid >> 6), l = tid & 63;
    int s_ = 0;
    #pragma unroll
    for (int j = 0; j < 8; ++j) s_ += mask[(size_t)b * 512 + j * 64 + l];
    #pragma unroll
    for (int k = 1; k < 64; k <<= 1) s_ += __shfl_xor(s_, k);
    if (l == 0) nreal[b] = s_ < 1 ? 1 : (s_ > 512 ? 512 : s_);
  }
}

// ---------------- zero out(acc) + denom ----------------
__global__ void zero_k(float4* __restrict__ acc4, float4* __restrict__ den4){
  int i = blockIdx.x * 256 + threadIdx.x;
  float4 z = {0.f, 0.f, 0.f, 0.f};
  acc4[i] = z;                 // grid covers exactly 1048576 float4 (= d_out)
  if (i < 4096) den4[i] = z;
}

// ---------------- qs[b*32+q][e] = (queries[q,e] + context[b]@cond_w[q*256+e] + cond_b)*scale*inv_t ----------------
__global__ __launch_bounds__(256) void calc_qs(
    const float* __restrict__ context, const float* __restrict__ queries,
    const float* __restrict__ logt, const float* __restrict__ condw,
    const float* __restrict__ condb, unsigned short* __restrict__ qs){
  __shared__ float ctx_l[64 * 64];
  int tid = threadIdx.x;
  int q   = blockIdx.x & 31;
  int b0  = (blockIdx.x >> 5) * 64;
  int qd  = q * 256 + tid;
  float4 cw[16];
  #pragma unroll
  for (int j = 0; j < 16; ++j) cw[j] = *(const float4*)(condw + (size_t)qd * 64 + 4 * j);
  float qbias = queries[qd] + condb[qd];
  float sc = 0.0625f * __expf(-logt[q >> 2]);      // scale * inv_temperature
  #pragma unroll
  for (int j = 0; j < 16; ++j){
    int f = j * 256 + tid;
    ctx_l[f] = context[(size_t)b0 * 64 + f];
  }
  __syncthreads();
  for (int b = 0; b < 64; ++b){
    const float4* cl = (const float4*)(ctx_l + b * 64);
    float acc = 0.f;
    #pragma unroll
    for (int j = 0; j < 16; ++j){
      float4 cv = cl[j]; float4 w4 = cw[j];
      acc += cv.x * w4.x + cv.y * w4.y + cv.z * w4.z + cv.w * w4.w;
    }
    qs[((size_t)(b0 + b) * 32 + q) * 256 + tid] = f2b((qbias + acc) * sc);
  }
}

// ---------------- qkp[row][d] = sum_e qs[row][e] * key_w[e][d]   (row = b*32+q) ----------------
__global__ __launch_bounds__(256) void calc_qkp(
    const unsigned short* __restrict__ qs, const unsigned short* __restrict__ wkt,
    unsigned short* __restrict__ qkp){
  __shared__ unsigned short at[64 * 256];
  int tid = threadIdx.x, w = tid >> 6, l = tid & 63, h = l >> 4, c = l & 15;
  size_t r0 = (size_t)blockIdx.x * 64;
  #pragma unroll
  for (int j = 0; j < 8; ++j){
    int f = j * 256 + tid;
    int row = f >> 5, col = (f & 31) * 8;
    bf16x8_t v = *(const bf16x8_t*)(qs + (r0 + row) * 256 + col);
    *(bf16x8_t*)&at[row * 256 + (col ^ ((row & 7) << 3))] = v;
  }
  __syncthreads();
  f32x4_t zero4 = {0.f, 0.f, 0.f, 0.f};
  f32x4_t acc[4][4];
  #pragma unroll
  for (int mt = 0; mt < 4; ++mt)
    #pragma unroll
    for (int nt = 0; nt < 4; ++nt) acc[mt][nt] = zero4;
  #pragma unroll
  for (int kk = 0; kk < 8; ++kk){
    bf16x8_t A[4];
    #pragma unroll
    for (int mt = 0; mt < 4; ++mt){
      int row = c + 16 * mt;
      A[mt] = *(const bf16x8_t*)&at[row * 256 + ((kk * 32 + 8 * h) ^ ((row & 7) << 3))];
    }
    #pragma unroll
    for (int nt = 0; nt < 4; ++nt){
      int d = 64 * w + 16 * nt + c;
      bf16x8_t Bv = *(const bf16x8_t*)(wkt + (size_t)d * 256 + kk * 32 + 8 * h);
      #pragma unroll
      for (int mt = 0; mt < 4; ++mt) acc[mt][nt] = MFMA16(A[mt], Bv, acc[mt][nt]);
    }
  }
  #pragma unroll
  for (int mt = 0; mt < 4; ++mt)
    #pragma unroll
    for (int nt = 0; nt < 4; ++nt)
      #pragma unroll
      for (int i = 0; i < 4; ++i){
        size_t row = r0 + 16 * mt + 4 * h + i;
        int d = 64 * w + 16 * nt + c;
        qkp[row * 256 + d] = f2b(acc[mt][nt][i]);
      }
}

// ---------------- one 32-row tile of the attention inner loop (macro: static reg ping-pong) ----------------
#define TILE_STEP(RX, ITV) do{                                                     \
    const int s0_ = sbase + (ITV) * 32;                                            \
    const float* knext_ = kptr + (size_t)((ITV) + 2) * (32 * 256);                 \
    const bool pf_ = ((ITV) + 2 < tend);                                           \
    _Pragma("unroll")                                                              \
    for (int j = 0; j < 8; ++j){                                                   \
      int row = 4 * j + w;                                                         \
      int d4 = 4 * l;                                                              \
      float4 kv = RX[j];                                                           \
      if (pf_) RX[j] = *(const float4*)(knext_ + j * 1024);                        \
      uint2 p;                                                                     \
      CVTPK(kv.x, kv.y, p.x);                                                      \
      CVTPK(kv.z, kv.w, p.y);                                                      \
      *(uint2*)&K[row * 256 + (d4 ^ ((row & 7) << 3))] = p;                        \
    }                                                                              \
    bar_lgkm();                          /* BAR1: K visible; loads in flight */    \
    f32x4_t as_ = zero4;                                                           \
    f32x4_t avT[2][4];                                                             \
    _Pragma("unroll")                                                              \
    for (int kk = 0; kk < 8; ++kk){                                                \
      int colk = kk * 32 + 8 * h;                                                  \
      bf16x8_t A0 = *(const bf16x8_t*)&K[c * 256 + (colk ^ ((c & 7) << 3))];       \
      bf16x8_t A1 = *(const bf16x8_t*)&K[(c + 16) * 256 + (colk ^ ((c & 7) << 3))];\
      as_ = MFMA16(mt ? A1 : A0, qf[kk], as_);                                     \
      if (kk == 2 * w){                                                            \
        avT[0][0] = MFMA16(A0, bIe, zero4);  avT[0][1] = MFMA16(A0, bIo, zero4);   \
        avT[1][0] = MFMA16(A1, bIe, zero4);  avT[1][1] = MFMA16(A1, bIo, zero4);   \
      }                                                                            \
      if (kk == 2 * w + 1){                                                        \
        avT[0][2] = MFMA16(A0, bIe, zero4);  avT[0][3] = MFMA16(A0, bIo, zero4);   \
        avT[1][2] = MFMA16(A1, bIe, zero4);  avT[1][3] = MFMA16(A1, bIo, zero4);   \
      }                                                                            \
    }                                                                              \
    _Pragma("unroll")                                                              \
    for (int m = 0; m < 2; ++m){                                                   \
      _Pragma("unroll")                                                            \
      for (int nt = 0; nt < 4; ++nt){                                              \
        int e = 64 * w + 16 * nt + c;                                              \
        int t0 = 16 * m + 4 * h;                                                   \
        uint2 p;                                                                   \
        CVTPK(avT[m][nt][0], avT[m][nt][1], p.x);                                  \
        CVTPK(avT[m][nt][2], avT[m][nt][3], p.y);                                  \
        *(uint2*)&vT[e * 32 + (t0 ^ ((e & 1) << 3))] = p;                          \
      }                                                                            \
    }                                                                              \
    {                                                                              \
      float e_[4]; float qs_ = 0.f;                                                \
      _Pragma("unroll")                                                            \
      for (int i = 0; i < 4; ++i){                                                 \
        int s = s0_ + 16 * mt + 4 * h + i;                                         \
        float ga = (float)(n_real - 1 - s);                                        \
        bool valid = (s < n_real);                                                 \
        float v = valid ? __expf(as_[i] - slope0 * ga) : 0.f;                      \
        e_[i] = v; qs_ += v;                                                       \
      }                                                                            \
      float r = qs_ + __shfl_xor(qs_, 16); r += __shfl_xor(r, 32);                 \
      if (l < 16) atomicAdd(&denl[16 * qt + c], r);                                \
      int q = 16 * qt + c;                                                         \
      int t0 = 16 * mt + 4 * h;                                                    \
      uint2 p;                                                                     \
      CVTPK(e_[0], e_[1], p.x);                                                    \
      CVTPK(e_[2], e_[3], p.y);                                                    \
      *(uint2*)&Pl[q * 32 + (t0 ^ ((q & 1) << 3))] = p;                            \
    }                                                                              \
    bar_lgkm();                          /* BAR2: vT/Pl visible; K consumed */     \
    {                                                                              \
      bf16x8_t Ap0 = *(const bf16x8_t*)&Pl[c * 32 + ((8 * h) ^ ((c & 1) << 3))];   \
      bf16x8_t Ap1 = *(const bf16x8_t*)&Pl[(16 + c) * 32 + ((8 * h) ^ ((c & 1) << 3))]; \
      _Pragma("unroll")                                                            \
      for (int nt = 0; nt < 4; ++nt){                                              \
        int e = 64 * w + 16 * nt + c;                                              \
        bf16x8_t Bv = *(const bf16x8_t*)&vT[e * 32 + ((8 * h) ^ ((e & 1) << 3))];  \
        ao[0][nt] = MFMA16(Ap0, Bv, ao[0][nt]);                                    \
        ao[1][nt] = MFMA16(Ap1, Bv, ao[1][nt]);                                    \
      }                                                                            \
    }                                                                              \
  } while(0)

// ---------------- partial attention over RAW keys: one block per (batch, 256-pos chunk) ----------------
// acc[q,e] += sum_s P[q,s] * keys[s,e] (atomics into d_out); Wv applied in epilogue GEMM.
// 2-deep register prefetch (RA/RB ping-pong, static indexing); lgkm-only barriers keep loads in flight.
__global__ __launch_bounds__(256, 2) void attn_part(
    const float* __restrict__ keys, const int* __restrict__ nreal,
    const unsigned short* __restrict__ qkp,
    float* __restrict__ acc, float* __restrict__ deng){
  __shared__ unsigned short K[32 * 256];   // bf16 keys, swizzled, 16 KB
  __shared__ unsigned short vT[256 * 32];  // K^T [e][t], swizzled, 16 KB
  __shared__ unsigned short Pl[32 * 32];   // P [q][t] bf16, 2 KB
  __shared__ float denl[32];

  int bid = blockIdx.x;
  int b = bid >> 1, ch = bid & 1;
  int n_real = nreal[b];
  int sbase = ch * 256;
  if (sbase >= n_real) return;                 // uniform early-exit, before any barrier

  int tid = threadIdx.x, w = tid >> 6, l = tid & 63, h = l >> 4, c = l & 15;
  int mt = w & 1, qt = w >> 1;
  if (tid < 32) denl[tid] = 0.f;

  // identity B-fragments for MFMA-transpose (exact for bf16 inputs)
  bf16x8_t bIe, bIo;
  #pragma unroll
  for (int j = 0; j < 8; ++j){
    bIe[j] = (h == (c >> 3)     && j == (c & 7)) ? (short)0x3F80 : (short)0;
    bIo[j] = (h == 2 + (c >> 3) && j == (c & 7)) ? (short)0x3F80 : (short)0;
  }

  int tend = (n_real - sbase + 31) >> 5; if (tend > 8) tend = 8;

  // 2-deep prefetch: RA <- tile0, RB <- tile1 (rows t = 4j + w, cols 4l..4l+3)
  const float* kptr = keys + ((size_t)b * 512 + sbase + w) * 256 + 4 * l;
  float4 RA[8], RB[8];
  #pragma unroll
  for (int j = 0; j < 8; ++j) RA[j] = *(const float4*)(kptr + j * 1024);
  if (tend > 1){
    #pragma unroll
    for (int j = 0; j < 8; ++j) RB[j] = *(const float4*)(kptr + 32 * 256 + j * 1024);
  }

  // this wave's qkp fragments (B-operand of logits MFMA)
  bf16x8_t qf[8];
  #pragma unroll
  for (int kk = 0; kk < 8; ++kk)
    qf[kk] = *(const bf16x8_t*)(qkp + ((size_t)b * 32 + 16 * qt + c) * 256 + kk * 32 + 8 * h);

  float slope0 = exp2f(-2.0f * (float)((c & 3) + 1));   // head = q&3

  f32x4_t zero4 = {0.f, 0.f, 0.f, 0.f};
  f32x4_t ao[2][4];
  #pragma unroll
  for (int q2 = 0; q2 < 2; ++q2)
    #pragma unroll
    for (int nt = 0; nt < 4; ++nt) ao[q2][nt] = zero4;

  for (int i0 = 0; i0 < 8; i0 += 2){
    if (i0 >= tend) break;
    TILE_STEP(RA, i0);
    if (i0 + 1 >= tend) break;
    TILE_STEP(RB, i0 + 1);
  }

  // ---- accumulate partial numerators / denominators (last BAR2 ordered denl) ----
  #pragma unroll
  for (int q2 = 0; q2 < 2; ++q2)
    #pragma unroll
    for (int nt = 0; nt < 4; ++nt){
      int e = 64 * w + 16 * nt + c;
      #pragma unroll
      for (int i = 0; i < 4; ++i){
        int q = 16 * q2 + 4 * h + i;
        atomicAdd(&acc[((size_t)b * 32 + q) * 256 + e], ao[q2][nt][i]);
      }
    }
  if (tid < 32) atomicAdd(&deng[b * 32 + tid], denl[tid]);
}

// ---------------- epilogue (IN-PLACE on d_out): out[row][e'] = sum_d (out[row][d]/den[row]) * value_w[e'][d] ----------------
__global__ __launch_bounds__(256) void vproj_norm(
    const float* __restrict__ deng, const unsigned short* __restrict__ wvb,
    float* __restrict__ out){
  __shared__ unsigned short at[64 * 256];
  __shared__ float dl[64];
  int tid = threadIdx.x, w = tid >> 6, l = tid & 63, h = l >> 4, c = l & 15;
  size_t r0 = (size_t)blockIdx.x * 64;
  if (tid < 64) dl[tid] = 1.f / deng[r0 + tid];
  __syncthreads();
  #pragma unroll
  for (int j = 0; j < 16; ++j){
    int idx = j * 256 + tid;
    int row = idx >> 6, c4 = (idx & 63) * 4;
    f32x4_t v = *(const f32x4_t*)(out + (r0 + row) * 256 + c4);
    float iv = dl[row];
    float v0 = v[0] * iv, v1 = v[1] * iv, v2 = v[2] * iv, v3 = v[3] * iv;
    uint2 p;
    CVTPK(v0, v1, p.x);
    CVTPK(v2, v3, p.y);
    *(uint2*)&at[row * 256 + (c4 ^ ((row & 7) << 3))] = p;
  }
  __syncthreads();
  f32x4_t zero4 = {0.f, 0.f, 0.f, 0.f};
  f32x4_t a2[4][4];
  #pragma unroll
  for (int m = 0; m < 4; ++m)
    #pragma unroll
    for (int nt = 0; nt < 4; ++nt) a2[m][nt] = zero4;
  #pragma unroll
  for (int kk = 0; kk < 8; ++kk){
    bf16x8_t A[4];
    #pragma unroll
    for (int m = 0; m < 4; ++m){
      int row = c + 16 * m;
      A[m] = *(const bf16x8_t*)&at[row * 256 + ((kk * 32 + 8 * h) ^ ((row & 7) << 3))];
    }
    #pragma unroll
    for (int nt = 0; nt < 4; ++nt){
      int ep = 64 * w + 16 * nt + c;
      bf16x8_t Bv = *(const bf16x8_t*)(wvb + (size_t)ep * 256 + kk * 32 + 8 * h);
      #pragma unroll
      for (int m = 0; m < 4; ++m) a2[m][nt] = MFMA16(A[m], Bv, a2[m][nt]);
    }
  }
  #pragma unroll
  for (int m = 0; m < 4; ++m)
    #pragma unroll
    for (int nt = 0; nt < 4; ++nt)
      #pragma unroll
      for (int i = 0; i < 4; ++i){
        size_t row = r0 + 16 * m + 4 * h + i;
        int ep = 64 * w + 16 * nt + c;
        out[row * 256 + ep] = a2[m][nt][i];
      }
}

extern "C" void kernel_launch(void* const* d_in, const int* in_sizes, int n_in,
                              void* d_out, int out_size, void* d_ws, size_t ws_size,
                              hipStream_t stream){
  const float* keys    = (const float*)d_in[0];
  const int*   mask    = (const int*)d_in[1];
  const float* context = (const float*)d_in[2];
  const float* queries = (const float*)d_in[3];
  const float* key_w   = (const float*)d_in[4];
  const float* value_w = (const float*)d_in[5];
  const float* logt    = (const float*)d_in[6];
  const float* cond_w  = (const float*)d_in[7];
  const float* cond_b  = (const float*)d_in[8];
  float* out = (float*)d_out;

  unsigned short* wkt = (unsigned short*)d_ws;           // 65536 bf16
  unsigned short* wvb = wkt + 65536;                     // 65536 bf16
  unsigned short* qs  = wvb + 65536;                     // 16384*256 bf16
  unsigned short* qkp = qs + (size_t)16384 * 256;        // 16384*256 bf16
  float* deng = (float*)(qkp + (size_t)16384 * 256);     // 16384 f32
  int*   nreal = (int*)(deng + 16384);                   // 512 int

  hipLaunchKernelGGL(setup_k,  dim3(384), dim3(256), 0, stream, key_w, value_w, mask, wkt, wvb, nreal);
  hipLaunchKernelGGL(calc_qs,  dim3(256), dim3(256), 0, stream, context, queries, logt, cond_w, cond_b, qs);
  hipLaunchKernelGGL(calc_qkp, dim3(256), dim3(256), 0, stream, qs, wkt, qkp);
  hipLaunchKernelGGL(zero_k,   dim3(4096), dim3(256), 0, stream, (float4*)out, (float4*)deng);
  hipLaunchKernelGGL(attn_part, dim3(1024), dim3(256), 0, stream, keys, nreal, qkp, out, deng);
  hipLaunchKernelGGL(vproj_norm, dim3(256), dim3(256), 0, stream, deng, wvb, out);
}

// Round 11
// 145.105 us; speedup vs baseline: 1.1589x; 1.1589x over previous
//
#include <hip/hip_runtime.h>

typedef short bf16x8_t __attribute__((ext_vector_type(8)));
typedef float f32x4_t  __attribute__((ext_vector_type(4)));

#define MFMA16(a,b,c) __builtin_amdgcn_mfma_f32_16x16x32_bf16(a,b,c,0,0,0)
#define CVTPK(lo, hi, dst) asm("v_cvt_pk_bf16_f32 %0, %1, %2" : "=v"(dst) : "v"(lo), "v"(hi))

__device__ __forceinline__ unsigned short f2b(float x){
  unsigned u = __float_as_uint(x);
  u += 0x7fffu + ((u >> 16) & 1u);
  return (unsigned short)(u >> 16);
}

__device__ __forceinline__ void bar_lgkm(){
  asm volatile("s_waitcnt lgkmcnt(0)" ::: "memory");
  __builtin_amdgcn_s_barrier();
  __builtin_amdgcn_sched_barrier(0);
}

// ---------------- setup: weights -> bf16 (blocks 0..255) + n_real (blocks 256..383) ----------------
__global__ void setup_k(const float* __restrict__ kw, const float* __restrict__ vw,
                        const int* __restrict__ mask,
                        unsigned short* __restrict__ wktb, unsigned short* __restrict__ wvb,
                        int* __restrict__ nreal){
  int bid = blockIdx.x, tid = threadIdx.x;
  if (bid < 256){
    int i = bid * 256 + tid;                       // 0..65535
    int d = i >> 8, e = i & 255;
    wktb[i] = f2b(kw[e * 256 + d]);                // WkT[d][e] (transposed, for calc_qkp)
    wvb[i]  = f2b(vw[i]);                          // value_w as-is (for vproj_norm)
  } else {
    int b = (bid - 256) * 4 + (tid >> 6), l = tid & 63;
    int s_ = 0;
    #pragma unroll
    for (int j = 0; j < 8; ++j) s_ += mask[(size_t)b * 512 + j * 64 + l];
    #pragma unroll
    for (int k = 1; k < 64; k <<= 1) s_ += __shfl_xor(s_, k);
    if (l == 0) nreal[b] = s_ < 1 ? 1 : (s_ > 512 ? 512 : s_);
  }
}

// ---------------- zero out(acc) + denom ----------------
__global__ void zero_k(float4* __restrict__ acc4, float4* __restrict__ den4){
  int i = blockIdx.x * 256 + threadIdx.x;
  float4 z = {0.f, 0.f, 0.f, 0.f};
  acc4[i] = z;                 // grid covers exactly 1048576 float4 (= d_out)
  if (i < 4096) den4[i] = z;
}

// ---------------- qs[b*32+q][e] = (queries[q,e] + context[b]@cond_w[q*256+e] + cond_b)*scale*inv_t ----------------
__global__ __launch_bounds__(256) void calc_qs(
    const float* __restrict__ context, const float* __restrict__ queries,
    const float* __restrict__ logt, const float* __restrict__ condw,
    const float* __restrict__ condb, unsigned short* __restrict__ qs){
  __shared__ float ctx_l[64 * 64];
  int tid = threadIdx.x;
  int q   = blockIdx.x & 31;
  int b0  = (blockIdx.x >> 5) * 64;
  int qd  = q * 256 + tid;
  float4 cw[16];
  #pragma unroll
  for (int j = 0; j < 16; ++j) cw[j] = *(const float4*)(condw + (size_t)qd * 64 + 4 * j);
  float qbias = queries[qd] + condb[qd];
  float sc = 0.0625f * __expf(-logt[q >> 2]);      // scale * inv_temperature
  #pragma unroll
  for (int j = 0; j < 16; ++j){
    int f = j * 256 + tid;
    ctx_l[f] = context[(size_t)b0 * 64 + f];
  }
  __syncthreads();
  for (int b = 0; b < 64; ++b){
    const float4* cl = (const float4*)(ctx_l + b * 64);
    float acc = 0.f;
    #pragma unroll
    for (int j = 0; j < 16; ++j){
      float4 cv = cl[j]; float4 w4 = cw[j];
      acc += cv.x * w4.x + cv.y * w4.y + cv.z * w4.z + cv.w * w4.w;
    }
    qs[((size_t)(b0 + b) * 32 + q) * 256 + tid] = f2b((qbias + acc) * sc);
  }
}

// ---------------- qkp[row][d] = sum_e qs[row][e] * key_w[e][d]   (row = b*32+q) ----------------
__global__ __launch_bounds__(256) void calc_qkp(
    const unsigned short* __restrict__ qs, const unsigned short* __restrict__ wkt,
    unsigned short* __restrict__ qkp){
  __shared__ unsigned short at[64 * 256];
  int tid = threadIdx.x, w = tid >> 6, l = tid & 63, h = l >> 4, c = l & 15;
  size_t r0 = (size_t)blockIdx.x * 64;
  #pragma unroll
  for (int j = 0; j < 8; ++j){
    int f = j * 256 + tid;
    int row = f >> 5, col = (f & 31) * 8;
    bf16x8_t v = *(const bf16x8_t*)(qs + (r0 + row) * 256 + col);
    *(bf16x8_t*)&at[row * 256 + (col ^ ((row & 7) << 3))] = v;
  }
  __syncthreads();
  f32x4_t zero4 = {0.f, 0.f, 0.f, 0.f};
  f32x4_t acc[4][4];
  #pragma unroll
  for (int mt = 0; mt < 4; ++mt)
    #pragma unroll
    for (int nt = 0; nt < 4; ++nt) acc[mt][nt] = zero4;
  #pragma unroll
  for (int kk = 0; kk < 8; ++kk){
    bf16x8_t A[4];
    #pragma unroll
    for (int mt = 0; mt < 4; ++mt){
      int row = c + 16 * mt;
      A[mt] = *(const bf16x8_t*)&at[row * 256 + ((kk * 32 + 8 * h) ^ ((row & 7) << 3))];
    }
    #pragma unroll
    for (int nt = 0; nt < 4; ++nt){
      int d = 64 * w + 16 * nt + c;
      bf16x8_t Bv = *(const bf16x8_t*)(wkt + (size_t)d * 256 + kk * 32 + 8 * h);
      #pragma unroll
      for (int mt = 0; mt < 4; ++mt) acc[mt][nt] = MFMA16(A[mt], Bv, acc[mt][nt]);
    }
  }
  #pragma unroll
  for (int mt = 0; mt < 4; ++mt)
    #pragma unroll
    for (int nt = 0; nt < 4; ++nt)
      #pragma unroll
      for (int i = 0; i < 4; ++i){
        size_t row = r0 + 16 * mt + 4 * h + i;
        int d = 64 * w + 16 * nt + c;
        qkp[row * 256 + d] = f2b(acc[mt][nt][i]);
      }
}

// ---------------- partial attention over RAW keys: one block per (batch, 256-pos chunk) ----------------
// acc[q,e] += sum_s P[q,s] * keys[s,e] (atomics into d_out); Wv applied in epilogue GEMM.
// R6 schedule: 1-deep reg prefetch, lgkm-only barriers, (256,3).
// Deltas vs R6: cvt_pk packing; denominator via MFMA(P, ones) in wave 0 (no shuffles, no LDS atomics).
__global__ __launch_bounds__(256, 3) void attn_part(
    const float* __restrict__ keys, const int* __restrict__ nreal,
    const unsigned short* __restrict__ qkp,
    float* __restrict__ acc, float* __restrict__ deng){
  __shared__ unsigned short K[32 * 256];   // bf16 keys, swizzled, 16 KB
  __shared__ unsigned short vT[256 * 32];  // K^T [e][t], swizzled, 16 KB
  __shared__ unsigned short Pl[32 * 32];   // P [q][t] bf16, 2 KB

  int bid = blockIdx.x;
  int b = bid >> 1, ch = bid & 1;
  int n_real = nreal[b];
  int sbase = ch * 256;
  if (sbase >= n_real) return;                 // uniform early-exit, before any barrier

  int tid = threadIdx.x, w = tid >> 6, l = tid & 63, h = l >> 4, c = l & 15;
  int mt = w & 1, qt = w >> 1;

  // identity B-fragments for MFMA-transpose (exact for bf16 inputs)
  bf16x8_t bIe, bIo;
  #pragma unroll
  for (int j = 0; j < 8; ++j){
    bIe[j] = (h == (c >> 3)     && j == (c & 7)) ? (short)0x3F80 : (short)0;
    bIo[j] = (h == 2 + (c >> 3) && j == (c & 7)) ? (short)0x3F80 : (short)0;
  }
  // ones B-fragment, column n=0 only (for denominator MFMA)
  bf16x8_t bOne;
  #pragma unroll
  for (int j = 0; j < 8; ++j) bOne[j] = (c == 0) ? (short)0x3F80 : (short)0;

  // stage tile 0 into registers (8 x dwordx4 per lane; rows t = 4j + w, cols 4l..4l+3)
  const float* kptr = keys + ((size_t)b * 512 + sbase + w) * 256 + 4 * l;
  float4 R[8];
  #pragma unroll
  for (int j = 0; j < 8; ++j) R[j] = *(const float4*)(kptr + j * 1024);

  // this wave's qkp fragments (B-operand of logits MFMA)
  bf16x8_t qf[8];
  #pragma unroll
  for (int kk = 0; kk < 8; ++kk)
    qf[kk] = *(const bf16x8_t*)(qkp + ((size_t)b * 32 + 16 * qt + c) * 256 + kk * 32 + 8 * h);

  float slope0 = exp2f(-2.0f * (float)((c & 3) + 1));   // head = q&3

  f32x4_t zero4 = {0.f, 0.f, 0.f, 0.f};
  f32x4_t ao[2][4];
  #pragma unroll
  for (int q2 = 0; q2 < 2; ++q2)
    #pragma unroll
    for (int nt = 0; nt < 4; ++nt) ao[q2][nt] = zero4;
  f32x4_t dv0 = zero4, dv1 = zero4;   // denominator accumulators (wave 0 only)

  int tend = (n_real - sbase + 31) >> 5; if (tend > 8) tend = 8;

  for (int it = 0; it < tend; ++it){
    int s0 = sbase + it * 32;
    // ---- convert R -> K (bf16, swizzled, cvt_pk); interleave issue of next tile's loads ----
    const float* knext = kptr + (size_t)(it + 1) * (32 * 256);
    #pragma unroll
    for (int j = 0; j < 8; ++j){
      int row = 4 * j + w;
      int d4 = 4 * l;
      float4 kv = R[j];
      if (it + 1 < tend) R[j] = *(const float4*)(knext + j * 1024);
      uint2 p;
      CVTPK(kv.x, kv.y, p.x);
      CVTPK(kv.z, kv.w, p.y);
      *(uint2*)&K[row * 256 + (d4 ^ ((row & 7) << 3))] = p;
    }
    bar_lgkm();                          // BAR1: K visible; staging loads stay in flight

    // ---- logits + K^T (via identity MFMA) ----
    f32x4_t as_ = zero4;
    f32x4_t avT[2][4];
    #pragma unroll
    for (int kk = 0; kk < 8; ++kk){
      int colk = kk * 32 + 8 * h;
      bf16x8_t A0 = *(const bf16x8_t*)&K[c * 256 + (colk ^ ((c & 7) << 3))];
      bf16x8_t A1 = *(const bf16x8_t*)&K[(c + 16) * 256 + (colk ^ ((c & 7) << 3))];
      as_ = MFMA16(mt ? A1 : A0, qf[kk], as_);
      if (kk == 2 * w){
        avT[0][0] = MFMA16(A0, bIe, zero4);  avT[0][1] = MFMA16(A0, bIo, zero4);
        avT[1][0] = MFMA16(A1, bIe, zero4);  avT[1][1] = MFMA16(A1, bIo, zero4);
      }
      if (kk == 2 * w + 1){
        avT[0][2] = MFMA16(A0, bIe, zero4);  avT[0][3] = MFMA16(A0, bIo, zero4);
        avT[1][2] = MFMA16(A1, bIe, zero4);  avT[1][3] = MFMA16(A1, bIo, zero4);
      }
    }
    // vT[e][t] <- K^T (each wave owns e-range 64w..64w+63)
    #pragma unroll
    for (int m = 0; m < 2; ++m)
      #pragma unroll
      for (int nt = 0; nt < 4; ++nt){
        int e = 64 * w + 16 * nt + c;
        int t0 = 16 * m + 4 * h;
        uint2 p;
        CVTPK(avT[m][nt][0], avT[m][nt][1], p.x);
        CVTPK(avT[m][nt][2], avT[m][nt][3], p.y);
        *(uint2*)&vT[e * 32 + (t0 ^ ((e & 1) << 3))] = p;
      }

    // ---- softmax (fixed-max): P = exp(logit - slope*games_ago), masked -> 0 ----
    {
      float e_[4];
      #pragma unroll
      for (int i = 0; i < 4; ++i){
        int s = s0 + 16 * mt + 4 * h + i;
        float ga = (float)(n_real - 1 - s);
        bool valid = (s < n_real);
        e_[i] = valid ? __expf(as_[i] - slope0 * ga) : 0.f;
      }
      int q = 16 * qt + c;
      int t0 = 16 * mt + 4 * h;
      uint2 p;
      CVTPK(e_[0], e_[1], p.x);
      CVTPK(e_[2], e_[3], p.y);
      *(uint2*)&Pl[q * 32 + (t0 ^ ((q & 1) << 3))] = p;
    }
    bar_lgkm();                          // BAR2: vT/Pl visible; K consumed

    // ---- PV over raw keys: ao[q][e] += P[q][t] * K[t][e]; denominator via MFMA(P, ones) ----
    {
      bf16x8_t Ap0 = *(const bf16x8_t*)&Pl[c * 32 + ((8 * h) ^ ((c & 1) << 3))];
      bf16x8_t Ap1 = *(const bf16x8_t*)&Pl[(16 + c) * 32 + ((8 * h) ^ ((c & 1) << 3))];
      if (w == 0){
        dv0 = MFMA16(Ap0, bOne, dv0);    // dv0[i] (at c==0) = sum_t P[4h+i][t]
        dv1 = MFMA16(Ap1, bOne, dv1);    // dv1[i] (at c==0) = sum_t P[16+4h+i][t]
      }
      #pragma unroll
      for (int nt = 0; nt < 4; ++nt){
        int e = 64 * w + 16 * nt + c;
        bf16x8_t Bv = *(const bf16x8_t*)&vT[e * 32 + ((8 * h) ^ ((e & 1) << 3))];
        ao[0][nt] = MFMA16(Ap0, Bv, ao[0][nt]);
        ao[1][nt] = MFMA16(Ap1, Bv, ao[1][nt]);
      }
    }
  }

  // ---- accumulate partial numerators / denominators ----
  #pragma unroll
  for (int q2 = 0; q2 < 2; ++q2)
    #pragma unroll
    for (int nt = 0; nt < 4; ++nt){
      int e = 64 * w + 16 * nt + c;
      #pragma unroll
      for (int i = 0; i < 4; ++i){
        int q = 16 * q2 + 4 * h + i;
        atomicAdd(&acc[((size_t)b * 32 + q) * 256 + e], ao[q2][nt][i]);
      }
    }
  if (w == 0 && c == 0){
    #pragma unroll
    for (int i = 0; i < 4; ++i){
      atomicAdd(&deng[b * 32 + 4 * h + i], dv0[i]);
      atomicAdd(&deng[b * 32 + 16 + 4 * h + i], dv1[i]);
    }
  }
}

// ---------------- epilogue (IN-PLACE on d_out): out[row][e'] = sum_d (out[row][d]/den[row]) * value_w[e'][d] ----------------
__global__ __launch_bounds__(256) void vproj_norm(
    const float* __restrict__ deng, const unsigned short* __restrict__ wvb,
    float* __restrict__ out){
  __shared__ unsigned short at[64 * 256];
  __shared__ float dl[64];
  int tid = threadIdx.x, w = tid >> 6, l = tid & 63, h = l >> 4, c = l & 15;
  size_t r0 = (size_t)blockIdx.x * 64;
  if (tid < 64) dl[tid] = 1.f / deng[r0 + tid];
  __syncthreads();
  #pragma unroll
  for (int j = 0; j < 16; ++j){
    int idx = j * 256 + tid;
    int row = idx >> 6, c4 = (idx & 63) * 4;
    f32x4_t v = *(const f32x4_t*)(out + (r0 + row) * 256 + c4);
    float iv = dl[row];
    float v0 = v[0] * iv, v1 = v[1] * iv, v2 = v[2] * iv, v3 = v[3] * iv;
    uint2 p;
    CVTPK(v0, v1, p.x);
    CVTPK(v2, v3, p.y);
    *(uint2*)&at[row * 256 + (c4 ^ ((row & 7) << 3))] = p;
  }
  __syncthreads();
  f32x4_t zero4 = {0.f, 0.f, 0.f, 0.f};
  f32x4_t a2[4][4];
  #pragma unroll
  for (int m = 0; m < 4; ++m)
    #pragma unroll
    for (int nt = 0; nt < 4; ++nt) a2[m][nt] = zero4;
  #pragma unroll
  for (int kk = 0; kk < 8; ++kk){
    bf16x8_t A[4];
    #pragma unroll
    for (int m = 0; m < 4; ++m){
      int row = c + 16 * m;
      A[m] = *(const bf16x8_t*)&at[row * 256 + ((kk * 32 + 8 * h) ^ ((row & 7) << 3))];
    }
    #pragma unroll
    for (int nt = 0; nt < 4; ++nt){
      int ep = 64 * w + 16 * nt + c;
      bf16x8_t Bv = *(const bf16x8_t*)(wvb + (size_t)ep * 256 + kk * 32 + 8 * h);
      #pragma unroll
      for (int m = 0; m < 4; ++m) a2[m][nt] = MFMA16(A[m], Bv, a2[m][nt]);
    }
  }
  #pragma unroll
  for (int m = 0; m < 4; ++m)
    #pragma unroll
    for (int nt = 0; nt < 4; ++nt)
      #pragma unroll
      for (int i = 0; i < 4; ++i){
        size_t row = r0 + 16 * m + 4 * h + i;
        int ep = 64 * w + 16 * nt + c;
        out[row * 256 + ep] = a2[m][nt][i];
      }
}

extern "C" void kernel_launch(void* const* d_in, const int* in_sizes, int n_in,
                              void* d_out, int out_size, void* d_ws, size_t ws_size,
                              hipStream_t stream){
  const float* keys    = (const float*)d_in[0];
  const int*   mask    = (const int*)d_in[1];
  const float* context = (const float*)d_in[2];
  const float* queries = (const float*)d_in[3];
  const float* key_w   = (const float*)d_in[4];
  const float* value_w = (const float*)d_in[5];
  const float* logt    = (const float*)d_in[6];
  const float* cond_w  = (const float*)d_in[7];
  const float* cond_b  = (const float*)d_in[8];
  float* out = (float*)d_out;

  unsigned short* wkt = (unsigned short*)d_ws;           // 65536 bf16
  unsigned short* wvb = wkt + 65536;                     // 65536 bf16
  unsigned short* qs  = wvb + 65536;                     // 16384*256 bf16
  unsigned short* qkp = qs + (size_t)16384 * 256;        // 16384*256 bf16
  float* deng = (float*)(qkp + (size_t)16384 * 256);     // 16384 f32
  int*   nreal = (int*)(deng + 16384);                   // 512 int

  hipLaunchKernelGGL(setup_k,  dim3(384), dim3(256), 0, stream, key_w, value_w, mask, wkt, wvb, nreal);
  hipLaunchKernelGGL(calc_qs,  dim3(256), dim3(256), 0, stream, context, queries, logt, cond_w, cond_b, qs);
  hipLaunchKernelGGL(calc_qkp, dim3(256), dim3(256), 0, stream, qs, wkt, qkp);
  hipLaunchKernelGGL(zero_k,   dim3(4096), dim3(256), 0, stream, (float4*)out, (float4*)deng);
  hipLaunchKernelGGL(attn_part, dim3(1024), dim3(256), 0, stream, keys, nreal, qkp, out, deng);
  hipLaunchKernelGGL(vproj_norm, dim3(256), dim3(256), 0, stream, deng, wvb, out);
}